// Round 2
// baseline (11814.932 us; speedup 1.0000x reference)
//
#include <hip/hip_runtime.h>
#include <hip/hip_bf16.h>
#include <cstdio>

// SHRED: 2-layer LSTM (B=64,T=512,I=64,H=512) + MLP decoder 512->1024->2048->16384.
//
// Round 2: ONE persistent kernel for the whole recurrence (was 513 launches).
//   256 WGs x 256 thr (1 WG/CU, all co-resident). Grid barrier = atomic counter,
//   release-add + acquire-spin at agent scope (cooperative-groups pattern).
//   WG w<128: layer0 utile w. WG w>=128: layer1 utile w-128 (pipeline-skewed:
//   iteration k computes h0[k] and h1[k-1]; only 1 barrier per iteration).
// Weights pre-packed once into MFMA A-fragment order, then held in REGISTERS
// for all 512 steps (layer1: 32 x bf16x8 = 128 VGPR). Cell state c in a
// register (1 float/lane). Only h traffic crosses memory.
// A-tile row order j_local = u_local*4 + gate  =>  with D mapping
// row=(lane>>4)*4+reg, col=lane&15, each lane's 4 regs are i,f,g,o of one
// (unit,batch) pair -> pointwise LSTM update is lane-local.

#define B_  64
#define T_  512
#define I_  64
#define H_  512
#define D1_ 1024
#define D2_ 2048
#define O_  16384

typedef __attribute__((ext_vector_type(8))) short bf16x8_t;
typedef __attribute__((ext_vector_type(4))) float f32x4_t;
typedef unsigned short ushort_t;

__device__ inline ushort_t f2bf(float f) {
    return __builtin_bit_cast(ushort_t, __float2bfloat16(f));
}
__device__ inline float sigm(float x) { return 1.0f / (1.0f + __expf(-x)); }
__device__ inline float tanhf_(float x) {
    float cx = fminf(fmaxf(x, -15.f), 15.f);
    float e = __expf(2.f * cx);
    return (e - 1.f) / (e + 1.f);
}

// ---- prep kernels (run once per call, cheap) -------------------------------

// packL0: [128 utiles][18 ksteps][64 lanes][8] bf16.
// A-frag: lane l holds rows j_local=l&15, k = kk*32 + 8*(l>>4) + i.
// j_local = u_local*4 + gate; weight row = gate*H + u.
// K-concat for layer0: [h0_prev (512) ; x_t (64)] -> Whh0 then Wih0.
__global__ void pack_l0(const float* __restrict__ Wih0, const float* __restrict__ Whh0,
                        ushort_t* __restrict__ pack) {
    int idx = blockIdx.x * 256 + threadIdx.x;       // < 128*18*64
    int l  = idx & 63;
    int kk = (idx >> 6) % 18;
    int tu = idx / (18 * 64);
    int jl = l & 15, g8 = (l >> 4) * 8;
    int gate = jl & 3, u = tu * 4 + (jl >> 2);
    int wrow = gate * H_ + u;
    int kg = kk * 32 + g8;                          // chunk of 8 never straddles 512
    const float* s = (kg < H_) ? (Whh0 + (size_t)wrow * H_ + kg)
                               : (Wih0 + (size_t)wrow * I_ + (kg - H_));
    ushort_t* d = pack + (size_t)idx * 8;
#pragma unroll
    for (int i = 0; i < 8; i++) d[i] = f2bf(s[i]);
}

// packL1: [128][32][64][8]. K-concat: [h0_t (512); h1_prev (512)] -> Wih1 then Whh1.
__global__ void pack_l1(const float* __restrict__ Wih1, const float* __restrict__ Whh1,
                        ushort_t* __restrict__ pack) {
    int idx = blockIdx.x * 256 + threadIdx.x;       // < 128*32*64
    int l  = idx & 63;
    int kk = (idx >> 6) & 31;
    int tu = idx >> 11;
    int jl = l & 15, g8 = (l >> 4) * 8;
    int gate = jl & 3, u = tu * 4 + (jl >> 2);
    int wrow = gate * H_ + u;
    int kg = kk * 32 + g8;
    const float* s = (kg < H_) ? (Wih1 + (size_t)wrow * H_ + kg)
                               : (Whh1 + (size_t)wrow * H_ + (kg - H_));
    ushort_t* d = pack + (size_t)idx * 8;
#pragma unroll
    for (int i = 0; i < 8; i++) d[i] = f2bf(s[i]);
}

// bsum[layer][u][gate] = bih[gate*H+u] + bhh[gate*H+u]
__global__ void pack_bias(const float* __restrict__ bih0, const float* __restrict__ bhh0,
                          const float* __restrict__ bih1, const float* __restrict__ bhh1,
                          float* __restrict__ bsum) {
    int idx = blockIdx.x * 256 + threadIdx.x;       // < 4096
    int layer = idx >> 11;
    int rest = idx & 2047;
    int u = rest >> 2, gate = rest & 3;
    const float* a = layer ? bih1 : bih0;
    const float* b = layer ? bhh1 : bhh0;
    bsum[idx] = a[gate * H_ + u] + b[gate * H_ + u];
}

// x[B][T][I] fp32 -> xbf[T][B][I] bf16
__global__ void conv_x(const float* __restrict__ x, ushort_t* __restrict__ xbf) {
    int idx = blockIdx.x * 256 + threadIdx.x;       // < 64*512*64
    int c = idx & 63;
    int t = (idx >> 6) & 511;
    int b = idx >> 15;
    xbf[(size_t)t * 4096 + b * 64 + c] = f2bf(x[idx]);
}

// ---- persistent recurrent kernel -------------------------------------------

__device__ inline void grid_barrier(unsigned int* cnt, int iter, int tid) {
    __syncthreads();    // all WG stores issued & drained (vmcnt) before arrival
    if (tid == 0) {
        __hip_atomic_fetch_add(cnt, 1u, __ATOMIC_RELEASE, __HIP_MEMORY_SCOPE_AGENT);
        unsigned int target = 256u * (unsigned int)(iter + 1);
        while (__hip_atomic_load(cnt, __ATOMIC_ACQUIRE, __HIP_MEMORY_SCOPE_AGENT) < target)
            __builtin_amdgcn_s_sleep(1);
    }
    __syncthreads();
}

template <int LAYER>
__device__ void run_layer(int tu, int tid,
                          const ushort_t* __restrict__ pack,
                          const float* __restrict__ bsum,
                          const ushort_t* __restrict__ xbf,
                          ushort_t* __restrict__ hbuf0,
                          ushort_t* __restrict__ hbuf1,
                          unsigned int* __restrict__ cnt)
{
    constexpr int NK = LAYER ? 32 : 18;
    int l = tid & 63, v = tid >> 6;
    int u_loc = l >> 4;
    int bb = v * 16 + (l & 15);
    int u = tu * 4 + u_loc;
    int g8 = u_loc * 8;

    // A-fragments: resident in VGPRs for the whole sequence.
    bf16x8_t aF[NK];
    {
        const ushort_t* src = pack + (size_t)tu * (NK * 512) + l * 8;
#pragma unroll
        for (int kk = 0; kk < NK; ++kk)
            aF[kk] = *(const bf16x8_t*)(src + kk * 512);
    }
    const float* bp = bsum + LAYER * 2048 + u * 4;
    float bi0 = bp[0], bi1 = bp[1], bi2 = bp[2], bi3 = bp[3];
    float creg = 0.0f;                              // cell state, lane-local

    const int HS = 64 * 512;
    for (int k = 0; k <= T_; ++k) {
        bool active = LAYER ? (k >= 1) : (k < T_);
        if (active) {
            // both layers read h0[k-1] from slot (k+1)&1
            const ushort_t* h0r = hbuf0 + ((k + 1) & 1) * HS + bb * 512;
            // layer0 K-tail: x_t ; layer1 K-tail: h1[k-2] slot k&1
            const ushort_t* srcHi = LAYER ? (hbuf1 + (k & 1) * HS + bb * 512)
                                          : (xbf + (size_t)k * 4096 + bb * 64);
            f32x4_t acc  = {bi0, bi1, bi2, bi3};
            f32x4_t acc2 = {0.f, 0.f, 0.f, 0.f};
#pragma unroll
            for (int kk = 0; kk < NK; ++kk) {
                const ushort_t* q = (kk < 16) ? (h0r + kk * 32 + g8)
                                              : (srcHi + (kk - 16) * 32 + g8);
                bf16x8_t bfr = *(const bf16x8_t*)q;
                if (kk & 1)
                    acc2 = __builtin_amdgcn_mfma_f32_16x16x32_bf16(aF[kk], bfr, acc2, 0, 0, 0);
                else
                    acc  = __builtin_amdgcn_mfma_f32_16x16x32_bf16(aF[kk], bfr, acc, 0, 0, 0);
            }
            acc = acc + acc2;
            // lane-local LSTM pointwise: regs = i,f,g,o of (u, bb)
            float xi = sigm(acc[0]);
            float xf = sigm(acc[1]);
            float xg = tanhf_(acc[2]);
            float xo = sigm(acc[3]);
            creg = xf * creg + xi * xg;
            float hn = xo * tanhf_(creg);
            // layer0 writes h0[k] slot k&1; layer1 writes h1[k-1] slot (k+1)&1
            ushort_t* hw = LAYER ? (hbuf1 + ((k + 1) & 1) * HS)
                                 : (hbuf0 + (k & 1) * HS);
            hw[(size_t)bb * 512 + u] = f2bf(hn);
        }
        grid_barrier(cnt, k, tid);
    }
}

__global__ __launch_bounds__(256) void lstm_persist(
    const ushort_t* __restrict__ packL0, const ushort_t* __restrict__ packL1,
    const float* __restrict__ bsum, const ushort_t* __restrict__ xbf,
    ushort_t* __restrict__ hbuf0, ushort_t* __restrict__ hbuf1,
    unsigned int* __restrict__ cnt)
{
    int w = blockIdx.x, tid = threadIdx.x;
    if (w < 128)
        run_layer<0>(w, tid, packL0, bsum, xbf, hbuf0, hbuf1, cnt);
    else
        run_layer<1>(w - 128, tid, packL1, bsum, xbf, hbuf0, hbuf1, cnt);
}

// ---- decoder GEMM: out[64][ncols] = act[64][K] @ W[ncols][K]^T + bias ------
template <int NK, bool RELU, bool OUTBF>
__global__ __launch_bounds__(256) void dec_gemm(
    const float* __restrict__ W, const float* __restrict__ bias,
    const ushort_t* __restrict__ act, void* __restrict__ outp, int ncols)
{
    int tile = blockIdx.x, tid = threadIdx.x;
    int l = tid & 63, v = tid >> 6;
    int bb = v * 16 + (l & 15);
    int jA = tile * 16 + (l & 15);
    int g8 = (l >> 4) * 8;
    const float* wrow = W + (size_t)jA * (NK * 32);
    const ushort_t* arow = act + (size_t)bb * (NK * 32);
    f32x4_t acc = {0.f, 0.f, 0.f, 0.f};
    for (int kk = 0; kk < NK; ++kk) {
        int kg = kk * 32 + g8;
        float4 w0 = *(const float4*)(wrow + kg);
        float4 w1 = *(const float4*)(wrow + kg + 4);
        bf16x8_t af;
        af[0] = (short)f2bf(w0.x); af[1] = (short)f2bf(w0.y);
        af[2] = (short)f2bf(w0.z); af[3] = (short)f2bf(w0.w);
        af[4] = (short)f2bf(w1.x); af[5] = (short)f2bf(w1.y);
        af[6] = (short)f2bf(w1.z); af[7] = (short)f2bf(w1.w);
        bf16x8_t bf = *(const bf16x8_t*)(arow + kg);
        acc = __builtin_amdgcn_mfma_f32_16x16x32_bf16(af, bf, acc, 0, 0, 0);
    }
    int j0 = tile * 16 + (l >> 4) * 4;
    float r[4];
#pragma unroll
    for (int i = 0; i < 4; i++) {
        r[i] = acc[i] + bias[j0 + i];
        if (RELU) r[i] = fmaxf(r[i], 0.f);
    }
    if (OUTBF) {
        ushort_t* o = (ushort_t*)outp + (size_t)bb * ncols + j0;
        unsigned int lo = (unsigned)f2bf(r[0]) | ((unsigned)f2bf(r[1]) << 16);
        unsigned int hi = (unsigned)f2bf(r[2]) | ((unsigned)f2bf(r[3]) << 16);
        uint2 q; q.x = lo; q.y = hi;
        *(uint2*)o = q;
    } else {
        float* o = (float*)outp + (size_t)bb * ncols + j0;
        float4 t4; t4.x = r[0]; t4.y = r[1]; t4.z = r[2]; t4.w = r[3];
        *(float4*)o = t4;
    }
}

// ---- host ------------------------------------------------------------------
extern "C" void kernel_launch(void* const* d_in, const int* in_sizes, int n_in,
                              void* d_out, int out_size, void* d_ws, size_t ws_size,
                              hipStream_t stream)
{
    const float* x    = (const float*)d_in[0];
    const float* Wih0 = (const float*)d_in[1];
    const float* Whh0 = (const float*)d_in[2];
    const float* bih0 = (const float*)d_in[3];
    const float* bhh0 = (const float*)d_in[4];
    const float* Wih1 = (const float*)d_in[5];
    const float* Whh1 = (const float*)d_in[6];
    const float* bih1 = (const float*)d_in[7];
    const float* bhh1 = (const float*)d_in[8];
    const float* W1   = (const float*)d_in[9];
    const float* b1   = (const float*)d_in[10];
    const float* W2   = (const float*)d_in[11];
    const float* b2   = (const float*)d_in[12];
    const float* W3   = (const float*)d_in[13];
    const float* b3   = (const float*)d_in[14];

    char* ws = (char*)d_ws;
    size_t off = 0;
    auto take = [&](size_t bytes) -> char* {
        char* p = ws + off;
        off = (off + bytes + 255) & ~(size_t)255;
        return p;
    };
    ushort_t* packL0 = (ushort_t*)take((size_t)128 * 18 * 64 * 8 * 2);  // 2.25 MiB
    ushort_t* packL1 = (ushort_t*)take((size_t)128 * 32 * 64 * 8 * 2);  // 4 MiB
    float*    bsum   = (float*)take(2 * 2048 * 4);
    ushort_t* xbf    = (ushort_t*)take((size_t)512 * 64 * 64 * 2);      // 4 MiB
    char* zbase = ws + off;
    ushort_t* hbuf0  = (ushort_t*)take(2 * 64 * 512 * 2);
    ushort_t* hbuf1  = (ushort_t*)take(2 * 64 * 512 * 2);
    unsigned int* cnt = (unsigned int*)take(256);
    size_t zbytes = (size_t)((ws + off) - zbase);
    ushort_t* y1 = (ushort_t*)take(64 * 1024 * 2);
    ushort_t* y2 = (ushort_t*)take(64 * 2048 * 2);
    if (off > ws_size) {
        fprintf(stderr, "kernel_launch: ws too small: need %zu have %zu\n", off, ws_size);
        return;
    }

    // prep (every call; deterministic)
    pack_l0<<<(128 * 18 * 64) / 256, 256, 0, stream>>>(Wih0, Whh0, packL0);
    pack_l1<<<(128 * 32 * 64) / 256, 256, 0, stream>>>(Wih1, Whh1, packL1);
    pack_bias<<<16, 256, 0, stream>>>(bih0, bhh0, bih1, bhh1, bsum);
    conv_x<<<(64 * 512 * 64) / 256, 256, 0, stream>>>(x, xbf);
    hipMemsetAsync(zbase, 0, zbytes, stream);   // zero h rings + barrier counter

    // whole recurrence in one persistent kernel (513 internal iterations)
    lstm_persist<<<256, 256, 0, stream>>>(packL0, packL1, bsum, xbf,
                                          hbuf0, hbuf1, cnt);

    // final top hidden state h1[511] lives in slot (511+2)&1 == 1
    const ushort_t* h1f = hbuf1 + 1 * (64 * 512);
    dec_gemm<16, true,  true ><<<  64, 256, 0, stream>>>(W1, b1, h1f, y1, D1_);
    dec_gemm<32, true,  true ><<< 128, 256, 0, stream>>>(W2, b2, y1, y2, D2_);
    dec_gemm<64, false, false><<<1024, 256, 0, stream>>>(W3, b3, y2, d_out, O_);
}

// Round 3
// 11629.610 us; speedup vs baseline: 1.0159x; 1.0159x over previous
//
#include <hip/hip_runtime.h>
#include <hip/hip_bf16.h>
#include <cstdio>

// SHRED: 2-layer LSTM (B=64,T=512,I=64,H=512) + MLP decoder 512->1024->2048->16384.
//
// Round 3: persistent kernel + FLAG-ARRAY grid barrier.
//   R2's single atomic counter serialized 256 RMWs (~89 ns each = 22.7 us/step).
//   Now: WG w release-stores iter+1 to flags[w] (distinct words, parallel);
//   each thread polls one flag (relaxed, agent scope); one acquire fence after.
// 256 WGs x 256 thr (1 WG/CU). WG w<128: layer0 utile w; else layer1 utile w-128.
// Pipeline-skewed: iteration k computes h0[k] and h1[k-1]; 1 barrier/iteration.
// Weights live in registers (A-fragments, packed once); cell state in a register.
// A-tile row order j_local = u_local*4 + gate => lane's 4 acc regs = i,f,g,o of
// one (unit,batch) pair -> pointwise update is lane-local.

#define B_  64
#define T_  512
#define I_  64
#define H_  512
#define D1_ 1024
#define D2_ 2048
#define O_  16384

typedef __attribute__((ext_vector_type(8))) short bf16x8_t;
typedef __attribute__((ext_vector_type(4))) float f32x4_t;
typedef unsigned short ushort_t;

__device__ inline ushort_t f2bf(float f) {
    return __builtin_bit_cast(ushort_t, __float2bfloat16(f));
}
__device__ inline float sigm(float x) { return 1.0f / (1.0f + __expf(-x)); }
__device__ inline float tanhf_(float x) {
    float cx = fminf(fmaxf(x, -15.f), 15.f);
    float e = __expf(2.f * cx);
    return (e - 1.f) / (e + 1.f);
}

// ---- prep kernels (run once per call, cheap) -------------------------------

// packL0: [128 utiles][18 ksteps][64 lanes][8] bf16.
// A-frag: lane l holds rows j_local=l&15, k = kk*32 + 8*(l>>4) + i.
// j_local = u_local*4 + gate; weight row = gate*H + u.
// K-concat for layer0: [h0_prev (512) ; x_t (64)] -> Whh0 then Wih0.
__global__ void pack_l0(const float* __restrict__ Wih0, const float* __restrict__ Whh0,
                        ushort_t* __restrict__ pack) {
    int idx = blockIdx.x * 256 + threadIdx.x;       // < 128*18*64
    int l  = idx & 63;
    int kk = (idx >> 6) % 18;
    int tu = idx / (18 * 64);
    int jl = l & 15, g8 = (l >> 4) * 8;
    int gate = jl & 3, u = tu * 4 + (jl >> 2);
    int wrow = gate * H_ + u;
    int kg = kk * 32 + g8;                          // chunk of 8 never straddles 512
    const float* s = (kg < H_) ? (Whh0 + (size_t)wrow * H_ + kg)
                               : (Wih0 + (size_t)wrow * I_ + (kg - H_));
    ushort_t* d = pack + (size_t)idx * 8;
#pragma unroll
    for (int i = 0; i < 8; i++) d[i] = f2bf(s[i]);
}

// packL1: [128][32][64][8]. K-concat: [h0_t (512); h1_prev (512)] -> Wih1 then Whh1.
__global__ void pack_l1(const float* __restrict__ Wih1, const float* __restrict__ Whh1,
                        ushort_t* __restrict__ pack) {
    int idx = blockIdx.x * 256 + threadIdx.x;       // < 128*32*64
    int l  = idx & 63;
    int kk = (idx >> 6) & 31;
    int tu = idx >> 11;
    int jl = l & 15, g8 = (l >> 4) * 8;
    int gate = jl & 3, u = tu * 4 + (jl >> 2);
    int wrow = gate * H_ + u;
    int kg = kk * 32 + g8;
    const float* s = (kg < H_) ? (Wih1 + (size_t)wrow * H_ + kg)
                               : (Whh1 + (size_t)wrow * H_ + (kg - H_));
    ushort_t* d = pack + (size_t)idx * 8;
#pragma unroll
    for (int i = 0; i < 8; i++) d[i] = f2bf(s[i]);
}

// bsum[layer][u][gate] = bih[gate*H+u] + bhh[gate*H+u]
__global__ void pack_bias(const float* __restrict__ bih0, const float* __restrict__ bhh0,
                          const float* __restrict__ bih1, const float* __restrict__ bhh1,
                          float* __restrict__ bsum) {
    int idx = blockIdx.x * 256 + threadIdx.x;       // < 4096
    int layer = idx >> 11;
    int rest = idx & 2047;
    int u = rest >> 2, gate = rest & 3;
    const float* a = layer ? bih1 : bih0;
    const float* b = layer ? bhh1 : bhh0;
    bsum[idx] = a[gate * H_ + u] + b[gate * H_ + u];
}

// x[B][T][I] fp32 -> xbf[T][B][I] bf16
__global__ void conv_x(const float* __restrict__ x, ushort_t* __restrict__ xbf) {
    int idx = blockIdx.x * 256 + threadIdx.x;       // < 64*512*64
    int c = idx & 63;
    int t = (idx >> 6) & 511;
    int b = idx >> 15;
    xbf[(size_t)t * 4096 + b * 64 + c] = f2bf(x[idx]);
}

// ---- persistent recurrent kernel -------------------------------------------

// Flag-array barrier: no RMW serialization. flags[w] counts completed iters
// of WG w (monotone). Release-store makes this XCD's dirty h lines visible;
// acquire fence after poll invalidates stale lines before next step's reads.
__device__ inline void grid_barrier(unsigned int* flags, int iter, int tid, int wg) {
    __syncthreads();    // drains vmcnt of all waves in the WG before arrival
    unsigned int target = (unsigned int)(iter + 1);
    if (tid == 0)
        __hip_atomic_store(&flags[wg], target, __ATOMIC_RELEASE,
                           __HIP_MEMORY_SCOPE_AGENT);
    // each of the 256 threads polls one WG's flag (coalesced 256B/wave/poll)
    while (__hip_atomic_load(&flags[tid], __ATOMIC_RELAXED,
                             __HIP_MEMORY_SCOPE_AGENT) < target)
        __builtin_amdgcn_s_sleep(1);
    __builtin_amdgcn_fence(__ATOMIC_ACQUIRE, "agent");
    __syncthreads();
}

template <int LAYER>
__device__ void run_layer(int tu, int tid, int wg,
                          const ushort_t* __restrict__ pack,
                          const float* __restrict__ bsum,
                          const ushort_t* __restrict__ xbf,
                          ushort_t* __restrict__ hbuf0,
                          ushort_t* __restrict__ hbuf1,
                          unsigned int* __restrict__ flags)
{
    constexpr int NK = LAYER ? 32 : 18;
    int l = tid & 63, v = tid >> 6;
    int u_loc = l >> 4;
    int bb = v * 16 + (l & 15);
    int u = tu * 4 + u_loc;
    int g8 = u_loc * 8;

    // A-fragments: resident in VGPRs/AGPRs for the whole sequence.
    bf16x8_t aF[NK];
    {
        const ushort_t* src = pack + (size_t)tu * (NK * 512) + l * 8;
#pragma unroll
        for (int kk = 0; kk < NK; ++kk)
            aF[kk] = *(const bf16x8_t*)(src + kk * 512);
    }
    const float* bp = bsum + LAYER * 2048 + u * 4;
    float bi0 = bp[0], bi1 = bp[1], bi2 = bp[2], bi3 = bp[3];
    float creg = 0.0f;                              // cell state, lane-local

    const int HS = 64 * 512;
    for (int k = 0; k <= T_; ++k) {
        bool active = LAYER ? (k >= 1) : (k < T_);
        if (active) {
            // both layers read h0[k-1] from slot (k+1)&1
            const ushort_t* h0r = hbuf0 + ((k + 1) & 1) * HS + bb * 512;
            // layer0 K-tail: x_t ; layer1 K-tail: h1[k-2] slot k&1
            const ushort_t* srcHi = LAYER ? (hbuf1 + (k & 1) * HS + bb * 512)
                                          : (xbf + (size_t)k * 4096 + bb * 64);
            f32x4_t acc  = {bi0, bi1, bi2, bi3};
            f32x4_t acc2 = {0.f, 0.f, 0.f, 0.f};
#pragma unroll
            for (int kk = 0; kk < NK; ++kk) {
                const ushort_t* q = (kk < 16) ? (h0r + kk * 32 + g8)
                                              : (srcHi + (kk - 16) * 32 + g8);
                bf16x8_t bfr = *(const bf16x8_t*)q;
                if (kk & 1)
                    acc2 = __builtin_amdgcn_mfma_f32_16x16x32_bf16(aF[kk], bfr, acc2, 0, 0, 0);
                else
                    acc  = __builtin_amdgcn_mfma_f32_16x16x32_bf16(aF[kk], bfr, acc, 0, 0, 0);
            }
            acc = acc + acc2;
            // lane-local LSTM pointwise: regs = i,f,g,o of (u, bb)
            float xi = sigm(acc[0]);
            float xf = sigm(acc[1]);
            float xg = tanhf_(acc[2]);
            float xo = sigm(acc[3]);
            creg = xf * creg + xi * xg;
            float hn = xo * tanhf_(creg);
            // layer0 writes h0[k] slot k&1; layer1 writes h1[k-1] slot (k+1)&1
            ushort_t* hw = LAYER ? (hbuf1 + ((k + 1) & 1) * HS)
                                 : (hbuf0 + (k & 1) * HS);
            hw[(size_t)bb * 512 + u] = f2bf(hn);
        }
        if (k < T_)                                  // last iter: no one reads after
            grid_barrier(flags, k, tid, wg);
    }
}

__global__ __launch_bounds__(256) void lstm_persist(
    const ushort_t* __restrict__ packL0, const ushort_t* __restrict__ packL1,
    const float* __restrict__ bsum, const ushort_t* __restrict__ xbf,
    ushort_t* __restrict__ hbuf0, ushort_t* __restrict__ hbuf1,
    unsigned int* __restrict__ flags)
{
    int w = blockIdx.x, tid = threadIdx.x;
    if (w < 128)
        run_layer<0>(w, tid, w, packL0, bsum, xbf, hbuf0, hbuf1, flags);
    else
        run_layer<1>(w - 128, tid, w, packL1, bsum, xbf, hbuf0, hbuf1, flags);
}

// ---- decoder GEMM: out[64][ncols] = act[64][K] @ W[ncols][K]^T + bias ------
template <int NK, bool RELU, bool OUTBF>
__global__ __launch_bounds__(256) void dec_gemm(
    const float* __restrict__ W, const float* __restrict__ bias,
    const ushort_t* __restrict__ act, void* __restrict__ outp, int ncols)
{
    int tile = blockIdx.x, tid = threadIdx.x;
    int l = tid & 63, v = tid >> 6;
    int bb = v * 16 + (l & 15);
    int jA = tile * 16 + (l & 15);
    int g8 = (l >> 4) * 8;
    const float* wrow = W + (size_t)jA * (NK * 32);
    const ushort_t* arow = act + (size_t)bb * (NK * 32);
    f32x4_t acc = {0.f, 0.f, 0.f, 0.f};
    for (int kk = 0; kk < NK; ++kk) {
        int kg = kk * 32 + g8;
        float4 w0 = *(const float4*)(wrow + kg);
        float4 w1 = *(const float4*)(wrow + kg + 4);
        bf16x8_t af;
        af[0] = (short)f2bf(w0.x); af[1] = (short)f2bf(w0.y);
        af[2] = (short)f2bf(w0.z); af[3] = (short)f2bf(w0.w);
        af[4] = (short)f2bf(w1.x); af[5] = (short)f2bf(w1.y);
        af[6] = (short)f2bf(w1.z); af[7] = (short)f2bf(w1.w);
        bf16x8_t bf = *(const bf16x8_t*)(arow + kg);
        acc = __builtin_amdgcn_mfma_f32_16x16x32_bf16(af, bf, acc, 0, 0, 0);
    }
    int j0 = tile * 16 + (l >> 4) * 4;
    float r[4];
#pragma unroll
    for (int i = 0; i < 4; i++) {
        r[i] = acc[i] + bias[j0 + i];
        if (RELU) r[i] = fmaxf(r[i], 0.f);
    }
    if (OUTBF) {
        ushort_t* o = (ushort_t*)outp + (size_t)bb * ncols + j0;
        unsigned int lo = (unsigned)f2bf(r[0]) | ((unsigned)f2bf(r[1]) << 16);
        unsigned int hi = (unsigned)f2bf(r[2]) | ((unsigned)f2bf(r[3]) << 16);
        uint2 q; q.x = lo; q.y = hi;
        *(uint2*)o = q;
    } else {
        float* o = (float*)outp + (size_t)bb * ncols + j0;
        float4 t4; t4.x = r[0]; t4.y = r[1]; t4.z = r[2]; t4.w = r[3];
        *(float4*)o = t4;
    }
}

// ---- host ------------------------------------------------------------------
extern "C" void kernel_launch(void* const* d_in, const int* in_sizes, int n_in,
                              void* d_out, int out_size, void* d_ws, size_t ws_size,
                              hipStream_t stream)
{
    const float* x    = (const float*)d_in[0];
    const float* Wih0 = (const float*)d_in[1];
    const float* Whh0 = (const float*)d_in[2];
    const float* bih0 = (const float*)d_in[3];
    const float* bhh0 = (const float*)d_in[4];
    const float* Wih1 = (const float*)d_in[5];
    const float* Whh1 = (const float*)d_in[6];
    const float* bih1 = (const float*)d_in[7];
    const float* bhh1 = (const float*)d_in[8];
    const float* W1   = (const float*)d_in[9];
    const float* b1   = (const float*)d_in[10];
    const float* W2   = (const float*)d_in[11];
    const float* b2   = (const float*)d_in[12];
    const float* W3   = (const float*)d_in[13];
    const float* b3   = (const float*)d_in[14];

    char* ws = (char*)d_ws;
    size_t off = 0;
    auto take = [&](size_t bytes) -> char* {
        char* p = ws + off;
        off = (off + bytes + 255) & ~(size_t)255;
        return p;
    };
    ushort_t* packL0 = (ushort_t*)take((size_t)128 * 18 * 64 * 8 * 2);  // 2.25 MiB
    ushort_t* packL1 = (ushort_t*)take((size_t)128 * 32 * 64 * 8 * 2);  // 4 MiB
    float*    bsum   = (float*)take(2 * 2048 * 4);
    ushort_t* xbf    = (ushort_t*)take((size_t)512 * 64 * 64 * 2);      // 4 MiB
    char* zbase = ws + off;
    ushort_t* hbuf0  = (ushort_t*)take(2 * 64 * 512 * 2);
    ushort_t* hbuf1  = (ushort_t*)take(2 * 64 * 512 * 2);
    unsigned int* flags = (unsigned int*)take(256 * 4);
    size_t zbytes = (size_t)((ws + off) - zbase);
    ushort_t* y1 = (ushort_t*)take(64 * 1024 * 2);
    ushort_t* y2 = (ushort_t*)take(64 * 2048 * 2);
    if (off > ws_size) {
        fprintf(stderr, "kernel_launch: ws too small: need %zu have %zu\n", off, ws_size);
        return;
    }

    // prep (every call; deterministic)
    pack_l0<<<(128 * 18 * 64) / 256, 256, 0, stream>>>(Wih0, Whh0, packL0);
    pack_l1<<<(128 * 32 * 64) / 256, 256, 0, stream>>>(Wih1, Whh1, packL1);
    pack_bias<<<16, 256, 0, stream>>>(bih0, bhh0, bih1, bhh1, bsum);
    conv_x<<<(64 * 512 * 64) / 256, 256, 0, stream>>>(x, xbf);
    hipMemsetAsync(zbase, 0, zbytes, stream);   // zero h rings + barrier flags

    // whole recurrence in one persistent kernel (513 internal iterations)
    lstm_persist<<<256, 256, 0, stream>>>(packL0, packL1, bsum, xbf,
                                          hbuf0, hbuf1, flags);

    // final top hidden state h1[511] lives in slot (511+2)&1 == 1
    const ushort_t* h1f = hbuf1 + 1 * (64 * 512);
    dec_gemm<16, true,  true ><<<  64, 256, 0, stream>>>(W1, b1, h1f, y1, D1_);
    dec_gemm<32, true,  true ><<< 128, 256, 0, stream>>>(W2, b2, y1, y2, D2_);
    dec_gemm<64, false, false><<<1024, 256, 0, stream>>>(W3, b3, y2, d_out, O_);
}

// Round 4
// 7610.824 us; speedup vs baseline: 1.5524x; 1.5280x over previous
//
#include <hip/hip_runtime.h>
#include <hip/hip_bf16.h>
#include <cstdio>

// SHRED: 2-layer LSTM (B=64,T=512,I=64,H=512) + MLP decoder 512->1024->2048->16384.
//
// Round 4: persistent kernel, NO acquire/release fences.
//   R2/R3 post-mortem: per-step agent-scope acquire/release lower to
//   buffer_inv sc1 / buffer_wbl2 sc1 = whole-L2 maintenance, ~22us/step
//   serialized at each XCD's TCC. Fix: all cross-barrier data (h rings, flags)
//   uses RELAXED agent-scope atomics -> plain sc1 ops that bypass L1/L2 and
//   are coherent at the MALL. No cache maintenance at all.
//   Ordering: h stores -> s_waitcnt vmcnt(0) -> __syncthreads -> flag store
//   (publish after data is at coherence point); readers poll flag then issue
//   sc1 loads (in-order issue + same coherence point => no fence).
// 256 WGs x 256 thr (1 WG/CU). WG w<128: layer0 utile w; else layer1 utile w-128.
// Pipeline-skewed: iteration k computes h0[k] and h1[k-1]; 1 barrier/iteration.
// Weights in registers (A-frags packed once); cell state in a register.
// A-tile row order j_local = u_local*4 + gate => lane's 4 acc regs = i,f,g,o
// of one (unit,batch) pair -> pointwise update lane-local.

#define B_  64
#define T_  512
#define I_  64
#define H_  512
#define D1_ 1024
#define D2_ 2048
#define O_  16384

typedef __attribute__((ext_vector_type(8))) short bf16x8_t;
typedef __attribute__((ext_vector_type(4))) float f32x4_t;
typedef unsigned short ushort_t;
typedef unsigned long long u64_t;

__device__ inline ushort_t f2bf(float f) {
    return __builtin_bit_cast(ushort_t, __float2bfloat16(f));
}
__device__ inline float sigm(float x) { return 1.0f / (1.0f + __expf(-x)); }
__device__ inline float tanhf_(float x) {
    float cx = fminf(fmaxf(x, -15.f), 15.f);
    float e = __expf(2.f * cx);
    return (e - 1.f) / (e + 1.f);
}

// relaxed agent-scope 8B load (global_load_dwordx2 ... sc1; no buffer_inv)
__device__ inline u64_t ld_dev(const void* p) {
    return __hip_atomic_load((const u64_t*)p, __ATOMIC_RELAXED,
                             __HIP_MEMORY_SCOPE_AGENT);
}

// ---- prep kernels (run once per call, cheap) -------------------------------

// packL0: [128 utiles][18 ksteps][64 lanes][8] bf16.
// A-frag: lane l holds rows j_local=l&15, k = kk*32 + 8*(l>>4) + i.
// j_local = u_local*4 + gate; weight row = gate*H + u.
// K-concat for layer0: [h0_prev (512) ; x_t (64)] -> Whh0 then Wih0.
__global__ void pack_l0(const float* __restrict__ Wih0, const float* __restrict__ Whh0,
                        ushort_t* __restrict__ pack) {
    int idx = blockIdx.x * 256 + threadIdx.x;       // < 128*18*64
    int l  = idx & 63;
    int kk = (idx >> 6) % 18;
    int tu = idx / (18 * 64);
    int jl = l & 15, g8 = (l >> 4) * 8;
    int gate = jl & 3, u = tu * 4 + (jl >> 2);
    int wrow = gate * H_ + u;
    int kg = kk * 32 + g8;                          // chunk of 8 never straddles 512
    const float* s = (kg < H_) ? (Whh0 + (size_t)wrow * H_ + kg)
                               : (Wih0 + (size_t)wrow * I_ + (kg - H_));
    ushort_t* d = pack + (size_t)idx * 8;
#pragma unroll
    for (int i = 0; i < 8; i++) d[i] = f2bf(s[i]);
}

// packL1: [128][32][64][8]. K-concat: [h0_t (512); h1_prev (512)] -> Wih1 then Whh1.
__global__ void pack_l1(const float* __restrict__ Wih1, const float* __restrict__ Whh1,
                        ushort_t* __restrict__ pack) {
    int idx = blockIdx.x * 256 + threadIdx.x;       // < 128*32*64
    int l  = idx & 63;
    int kk = (idx >> 6) & 31;
    int tu = idx >> 11;
    int jl = l & 15, g8 = (l >> 4) * 8;
    int gate = jl & 3, u = tu * 4 + (jl >> 2);
    int wrow = gate * H_ + u;
    int kg = kk * 32 + g8;
    const float* s = (kg < H_) ? (Wih1 + (size_t)wrow * H_ + kg)
                               : (Whh1 + (size_t)wrow * H_ + (kg - H_));
    ushort_t* d = pack + (size_t)idx * 8;
#pragma unroll
    for (int i = 0; i < 8; i++) d[i] = f2bf(s[i]);
}

// bsum[layer][u][gate] = bih[gate*H+u] + bhh[gate*H+u]
__global__ void pack_bias(const float* __restrict__ bih0, const float* __restrict__ bhh0,
                          const float* __restrict__ bih1, const float* __restrict__ bhh1,
                          float* __restrict__ bsum) {
    int idx = blockIdx.x * 256 + threadIdx.x;       // < 4096
    int layer = idx >> 11;
    int rest = idx & 2047;
    int u = rest >> 2, gate = rest & 3;
    const float* a = layer ? bih1 : bih0;
    const float* b = layer ? bhh1 : bhh0;
    bsum[idx] = a[gate * H_ + u] + b[gate * H_ + u];
}

// x[B][T][I] fp32 -> xbf[T][B][I] bf16
__global__ void conv_x(const float* __restrict__ x, ushort_t* __restrict__ xbf) {
    int idx = blockIdx.x * 256 + threadIdx.x;       // < 64*512*64
    int c = idx & 63;
    int t = (idx >> 6) & 511;
    int b = idx >> 15;
    xbf[(size_t)t * 4096 + b * 64 + c] = f2bf(x[idx]);
}

// ---- persistent recurrent kernel -------------------------------------------

// Fence-free barrier. flags[w] = completed iters of WG w (monotone).
// All stores before this are sc1 (at MALL); vmcnt(0) guarantees completion;
// flag publish is also sc1. Readers poll sc1 -> data at MALL is visible.
__device__ inline void grid_barrier(unsigned int* flags, int iter, int tid, int wg) {
    asm volatile("s_waitcnt vmcnt(0)" ::: "memory");    // own stores at MALL
    __syncthreads();                                     // whole WG done
    unsigned int target = (unsigned int)(iter + 1);
    if (tid == 0)
        __hip_atomic_store(&flags[wg], target, __ATOMIC_RELAXED,
                           __HIP_MEMORY_SCOPE_AGENT);
    while (__hip_atomic_load(&flags[tid], __ATOMIC_RELAXED,
                             __HIP_MEMORY_SCOPE_AGENT) < target)
        __builtin_amdgcn_s_sleep(1);
    __syncthreads();                                     // compiler+WG barrier
}

template <int LAYER>
__device__ void run_layer(int tu, int tid, int wg,
                          const ushort_t* __restrict__ pack,
                          const float* __restrict__ bsum,
                          const ushort_t* __restrict__ xbf,
                          ushort_t* __restrict__ hbuf0,
                          ushort_t* __restrict__ hbuf1,
                          unsigned int* __restrict__ flags)
{
    constexpr int NK = LAYER ? 32 : 18;
    int l = tid & 63, v = tid >> 6;
    int u_loc = l >> 4;
    int bb = v * 16 + (l & 15);
    int u = tu * 4 + u_loc;
    int g8 = u_loc * 8;

    // A-fragments: resident in VGPRs/AGPRs for the whole sequence.
    bf16x8_t aF[NK];
    {
        const ushort_t* src = pack + (size_t)tu * (NK * 512) + l * 8;
#pragma unroll
        for (int kk = 0; kk < NK; ++kk)
            aF[kk] = *(const bf16x8_t*)(src + kk * 512);
    }
    const float* bp = bsum + LAYER * 2048 + u * 4;
    float bi0 = bp[0], bi1 = bp[1], bi2 = bp[2], bi3 = bp[3];
    float creg = 0.0f;                              // cell state, lane-local

    const int HS = 64 * 512;
    for (int k = 0; k <= T_; ++k) {
        bool active = LAYER ? (k >= 1) : (k < T_);
        if (active) {
            // both layers read h0[k-1] from slot (k+1)&1
            const ushort_t* h0r = hbuf0 + ((k + 1) & 1) * HS + bb * 512;
            // layer0 K-tail: x_t (read-only, plain cached);
            // layer1 K-tail: h1[k-2] slot k&1 (sc1)
            const ushort_t* srcHi = LAYER ? (hbuf1 + (k & 1) * HS + bb * 512)
                                          : (xbf + (size_t)k * 4096 + bb * 64);
            // load all B-fragments first (bypass loads pipeline at the MALL)
            bf16x8_t bfr[NK];
#pragma unroll
            for (int kk = 0; kk < NK; ++kk) {
                if (kk < 16 || LAYER) {
                    const ushort_t* q = (kk < 16) ? (h0r + kk * 32 + g8)
                                                  : (srcHi + (kk - 16) * 32 + g8);
                    union { u64_t q2[2]; bf16x8_t v; } uu;
                    uu.q2[0] = ld_dev(q);
                    uu.q2[1] = ld_dev(q + 4);
                    bfr[kk] = uu.v;
                } else {
                    bfr[kk] = *(const bf16x8_t*)(srcHi + (kk - 16) * 32 + g8);
                }
            }
            f32x4_t acc  = {bi0, bi1, bi2, bi3};
            f32x4_t acc2 = {0.f, 0.f, 0.f, 0.f};
#pragma unroll
            for (int kk = 0; kk < NK; ++kk) {
                if (kk & 1)
                    acc2 = __builtin_amdgcn_mfma_f32_16x16x32_bf16(aF[kk], bfr[kk], acc2, 0, 0, 0);
                else
                    acc  = __builtin_amdgcn_mfma_f32_16x16x32_bf16(aF[kk], bfr[kk], acc, 0, 0, 0);
            }
            acc = acc + acc2;
            // lane-local LSTM pointwise: regs = i,f,g,o of (u, bb)
            float xi = sigm(acc[0]);
            float xf = sigm(acc[1]);
            float xg = tanhf_(acc[2]);
            float xo = sigm(acc[3]);
            creg = xf * creg + xi * xg;
            float hn = xo * tanhf_(creg);
            // layer0 writes h0[k] slot k&1; layer1 writes h1[k-1] slot (k+1)&1
            ushort_t* hw = LAYER ? (hbuf1 + ((k + 1) & 1) * HS)
                                 : (hbuf0 + (k & 1) * HS);
            // pair lanes (u, u+1) of same bb -> one 4B relaxed sc1 store
            unsigned int mine = (unsigned int)f2bf(hn);
            unsigned int other = (unsigned int)__shfl_xor((int)mine, 16, 64);
            if ((u_loc & 1) == 0) {
                unsigned int valp = mine | (other << 16);
                __hip_atomic_store((unsigned int*)(hw + (size_t)bb * 512 + u), valp,
                                   __ATOMIC_RELAXED, __HIP_MEMORY_SCOPE_AGENT);
            }
        }
        if (k < T_)                                  // last iter: no one reads after
            grid_barrier(flags, k, tid, wg);
    }
}

__global__ __launch_bounds__(256) void lstm_persist(
    const ushort_t* __restrict__ packL0, const ushort_t* __restrict__ packL1,
    const float* __restrict__ bsum, const ushort_t* __restrict__ xbf,
    ushort_t* __restrict__ hbuf0, ushort_t* __restrict__ hbuf1,
    unsigned int* __restrict__ flags)
{
    int w = blockIdx.x, tid = threadIdx.x;
    if (w < 128)
        run_layer<0>(w, tid, w, packL0, bsum, xbf, hbuf0, hbuf1, flags);
    else
        run_layer<1>(w - 128, tid, w, packL1, bsum, xbf, hbuf0, hbuf1, flags);
}

// ---- decoder GEMM: out[64][ncols] = act[64][K] @ W[ncols][K]^T + bias ------
template <int NK, bool RELU, bool OUTBF>
__global__ __launch_bounds__(256) void dec_gemm(
    const float* __restrict__ W, const float* __restrict__ bias,
    const ushort_t* __restrict__ act, void* __restrict__ outp, int ncols)
{
    int tile = blockIdx.x, tid = threadIdx.x;
    int l = tid & 63, v = tid >> 6;
    int bb = v * 16 + (l & 15);
    int jA = tile * 16 + (l & 15);
    int g8 = (l >> 4) * 8;
    const float* wrow = W + (size_t)jA * (NK * 32);
    const ushort_t* arow = act + (size_t)bb * (NK * 32);
    f32x4_t acc = {0.f, 0.f, 0.f, 0.f};
    for (int kk = 0; kk < NK; ++kk) {
        int kg = kk * 32 + g8;
        float4 w0 = *(const float4*)(wrow + kg);
        float4 w1 = *(const float4*)(wrow + kg + 4);
        bf16x8_t af;
        af[0] = (short)f2bf(w0.x); af[1] = (short)f2bf(w0.y);
        af[2] = (short)f2bf(w0.z); af[3] = (short)f2bf(w0.w);
        af[4] = (short)f2bf(w1.x); af[5] = (short)f2bf(w1.y);
        af[6] = (short)f2bf(w1.z); af[7] = (short)f2bf(w1.w);
        bf16x8_t bf = *(const bf16x8_t*)(arow + kg);
        acc = __builtin_amdgcn_mfma_f32_16x16x32_bf16(af, bf, acc, 0, 0, 0);
    }
    int j0 = tile * 16 + (l >> 4) * 4;
    float r[4];
#pragma unroll
    for (int i = 0; i < 4; i++) {
        r[i] = acc[i] + bias[j0 + i];
        if (RELU) r[i] = fmaxf(r[i], 0.f);
    }
    if (OUTBF) {
        ushort_t* o = (ushort_t*)outp + (size_t)bb * ncols + j0;
        unsigned int lo = (unsigned)f2bf(r[0]) | ((unsigned)f2bf(r[1]) << 16);
        unsigned int hi = (unsigned)f2bf(r[2]) | ((unsigned)f2bf(r[3]) << 16);
        uint2 q; q.x = lo; q.y = hi;
        *(uint2*)o = q;
    } else {
        float* o = (float*)outp + (size_t)bb * ncols + j0;
        float4 t4; t4.x = r[0]; t4.y = r[1]; t4.z = r[2]; t4.w = r[3];
        *(float4*)o = t4;
    }
}

// ---- host ------------------------------------------------------------------
extern "C" void kernel_launch(void* const* d_in, const int* in_sizes, int n_in,
                              void* d_out, int out_size, void* d_ws, size_t ws_size,
                              hipStream_t stream)
{
    const float* x    = (const float*)d_in[0];
    const float* Wih0 = (const float*)d_in[1];
    const float* Whh0 = (const float*)d_in[2];
    const float* bih0 = (const float*)d_in[3];
    const float* bhh0 = (const float*)d_in[4];
    const float* Wih1 = (const float*)d_in[5];
    const float* Whh1 = (const float*)d_in[6];
    const float* bih1 = (const float*)d_in[7];
    const float* bhh1 = (const float*)d_in[8];
    const float* W1   = (const float*)d_in[9];
    const float* b1   = (const float*)d_in[10];
    const float* W2   = (const float*)d_in[11];
    const float* b2   = (const float*)d_in[12];
    const float* W3   = (const float*)d_in[13];
    const float* b3   = (const float*)d_in[14];

    char* ws = (char*)d_ws;
    size_t off = 0;
    auto take = [&](size_t bytes) -> char* {
        char* p = ws + off;
        off = (off + bytes + 255) & ~(size_t)255;
        return p;
    };
    ushort_t* packL0 = (ushort_t*)take((size_t)128 * 18 * 64 * 8 * 2);  // 2.25 MiB
    ushort_t* packL1 = (ushort_t*)take((size_t)128 * 32 * 64 * 8 * 2);  // 4 MiB
    float*    bsum   = (float*)take(2 * 2048 * 4);
    ushort_t* xbf    = (ushort_t*)take((size_t)512 * 64 * 64 * 2);      // 4 MiB
    char* zbase = ws + off;
    ushort_t* hbuf0  = (ushort_t*)take(2 * 64 * 512 * 2);
    ushort_t* hbuf1  = (ushort_t*)take(2 * 64 * 512 * 2);
    unsigned int* flags = (unsigned int*)take(256 * 4);
    size_t zbytes = (size_t)((ws + off) - zbase);
    ushort_t* y1 = (ushort_t*)take(64 * 1024 * 2);
    ushort_t* y2 = (ushort_t*)take(64 * 2048 * 2);
    if (off > ws_size) {
        fprintf(stderr, "kernel_launch: ws too small: need %zu have %zu\n", off, ws_size);
        return;
    }

    // prep (every call; deterministic)
    pack_l0<<<(128 * 18 * 64) / 256, 256, 0, stream>>>(Wih0, Whh0, packL0);
    pack_l1<<<(128 * 32 * 64) / 256, 256, 0, stream>>>(Wih1, Whh1, packL1);
    pack_bias<<<16, 256, 0, stream>>>(bih0, bhh0, bih1, bhh1, bsum);
    conv_x<<<(64 * 512 * 64) / 256, 256, 0, stream>>>(x, xbf);
    hipMemsetAsync(zbase, 0, zbytes, stream);   // zero h rings + barrier flags

    // whole recurrence in one persistent kernel (513 internal iterations)
    lstm_persist<<<256, 256, 0, stream>>>(packL0, packL1, bsum, xbf,
                                          hbuf0, hbuf1, flags);

    // final top hidden state h1[511] lives in slot (511+2)&1 == 1
    const ushort_t* h1f = hbuf1 + 1 * (64 * 512);
    dec_gemm<16, true,  true ><<<  64, 256, 0, stream>>>(W1, b1, h1f, y1, D1_);
    dec_gemm<32, true,  true ><<< 128, 256, 0, stream>>>(W2, b2, y1, y2, D2_);
    dec_gemm<64, false, false><<<1024, 256, 0, stream>>>(W3, b3, y2, d_out, O_);
}

// Round 5
// 5429.060 us; speedup vs baseline: 2.1762x; 1.4019x over previous
//
#include <hip/hip_runtime.h>
#include <hip/hip_bf16.h>
#include <cstdio>

// SHRED: 2-layer LSTM (B=64,T=512,I=64,H=512) + MLP decoder 512->1024->2048->16384.
//
// Round 5: persistent kernel, register-resident everything, ISA-level sc1 loads.
//   R4 post-mortem: VGPR_Count=92 << ~260 needed => bfr[]/aF spilled to scratch
//   (L2-resident, invisible in FETCH, serial latency). Fixes:
//   (1) __launch_bounds__(256,1): full unified VGPR/AGPR budget at 1 WG/CU.
//   (2) B-frags via inline-asm global_load_dwordx4 sc0 sc1 (plain ISA loads,
//       pipelined, 16B/lane), one s_waitcnt vmcnt(0)+sched_barrier before MFMAs.
//   (3) Poll diet: wave 0 only; lane l polls flags[4l..4l+3] via one dwordx4 sc1.
// Barrier protocol (fence-free, from R4): h stores sc1 -> vmcnt(0) ->
//   __syncthreads -> tid0 flag store (sc1) -> wave0 polls all flags -> sync.
// WG w<128: layer0 utile w; else layer1 utile w-128. Pipeline-skewed:
//   iteration k computes h0[k] and h1[k-1]; 1 barrier per iteration.
// A-tile row order j_local = u_local*4 + gate => lane's 4 acc regs = i,f,g,o
// of one (unit,batch) pair -> pointwise update lane-local; cell state in reg.

#define B_  64
#define T_  512
#define I_  64
#define H_  512
#define D1_ 1024
#define D2_ 2048
#define O_  16384

typedef __attribute__((ext_vector_type(8))) short bf16x8_t;
typedef __attribute__((ext_vector_type(4))) float f32x4_t;
typedef unsigned short ushort_t;

__device__ inline ushort_t f2bf(float f) {
    return __builtin_bit_cast(ushort_t, __float2bfloat16(f));
}
__device__ inline float sigm(float x) { return 1.0f / (1.0f + __expf(-x)); }
__device__ inline float tanhf_(float x) {
    float cx = fminf(fmaxf(x, -15.f), 15.f);
    float e = __expf(2.f * cx);
    return (e - 1.f) / (e + 1.f);
}

// ---- prep kernels (run once per call, cheap) -------------------------------

// packL0: [128 utiles][18 ksteps][64 lanes][8] bf16.
// A-frag: lane l holds rows j_local=l&15, k = kk*32 + 8*(l>>4) + i.
// j_local = u_local*4 + gate; weight row = gate*H + u.
// K-concat for layer0: [h0_prev (512) ; x_t (64)] -> Whh0 then Wih0.
__global__ void pack_l0(const float* __restrict__ Wih0, const float* __restrict__ Whh0,
                        ushort_t* __restrict__ pack) {
    int idx = blockIdx.x * 256 + threadIdx.x;       // < 128*18*64
    int l  = idx & 63;
    int kk = (idx >> 6) % 18;
    int tu = idx / (18 * 64);
    int jl = l & 15, g8 = (l >> 4) * 8;
    int gate = jl & 3, u = tu * 4 + (jl >> 2);
    int wrow = gate * H_ + u;
    int kg = kk * 32 + g8;                          // chunk of 8 never straddles 512
    const float* s = (kg < H_) ? (Whh0 + (size_t)wrow * H_ + kg)
                               : (Wih0 + (size_t)wrow * I_ + (kg - H_));
    ushort_t* d = pack + (size_t)idx * 8;
#pragma unroll
    for (int i = 0; i < 8; i++) d[i] = f2bf(s[i]);
}

// packL1: [128][32][64][8]. K-concat: [h0_t (512); h1_prev (512)] -> Wih1 then Whh1.
__global__ void pack_l1(const float* __restrict__ Wih1, const float* __restrict__ Whh1,
                        ushort_t* __restrict__ pack) {
    int idx = blockIdx.x * 256 + threadIdx.x;       // < 128*32*64
    int l  = idx & 63;
    int kk = (idx >> 6) & 31;
    int tu = idx >> 11;
    int jl = l & 15, g8 = (l >> 4) * 8;
    int gate = jl & 3, u = tu * 4 + (jl >> 2);
    int wrow = gate * H_ + u;
    int kg = kk * 32 + g8;
    const float* s = (kg < H_) ? (Wih1 + (size_t)wrow * H_ + kg)
                               : (Whh1 + (size_t)wrow * H_ + (kg - H_));
    ushort_t* d = pack + (size_t)idx * 8;
#pragma unroll
    for (int i = 0; i < 8; i++) d[i] = f2bf(s[i]);
}

// bsum[layer][u][gate] = bih[gate*H+u] + bhh[gate*H+u]
__global__ void pack_bias(const float* __restrict__ bih0, const float* __restrict__ bhh0,
                          const float* __restrict__ bih1, const float* __restrict__ bhh1,
                          float* __restrict__ bsum) {
    int idx = blockIdx.x * 256 + threadIdx.x;       // < 4096
    int layer = idx >> 11;
    int rest = idx & 2047;
    int u = rest >> 2, gate = rest & 3;
    const float* a = layer ? bih1 : bih0;
    const float* b = layer ? bhh1 : bhh0;
    bsum[idx] = a[gate * H_ + u] + b[gate * H_ + u];
}

// x[B][T][I] fp32 -> xbf[T][B][I] bf16
__global__ void conv_x(const float* __restrict__ x, ushort_t* __restrict__ xbf) {
    int idx = blockIdx.x * 256 + threadIdx.x;       // < 64*512*64
    int c = idx & 63;
    int t = (idx >> 6) & 511;
    int b = idx >> 15;
    xbf[(size_t)t * 4096 + b * 64 + c] = f2bf(x[idx]);
}

// ---- persistent recurrent kernel -------------------------------------------

// Fence-free barrier. flags[w] = completed iters of WG w (monotone, sc1).
// Entry: per-wave vmcnt(0) drains own sc1 h-stores; syncthreads joins WG;
// tid0 publishes; wave 0 polls ALL 256 flags (4/lane, one dwordx4 sc1);
// final syncthreads releases the WG.
__device__ inline void grid_barrier(unsigned int* flags, int iter, int tid, int wg) {
    asm volatile("s_waitcnt vmcnt(0)" ::: "memory");    // own stores at MALL
    __syncthreads();                                     // whole WG done
    unsigned int target = (unsigned int)(iter + 1);
    if (tid == 0)
        __hip_atomic_store(&flags[wg], target, __ATOMIC_RELAXED,
                           __HIP_MEMORY_SCOPE_AGENT);
    if (tid < 64) {
        const uint4* fp = (const uint4*)flags;
        for (;;) {
            uint4 f;
            asm volatile("global_load_dwordx4 %0, %1, off sc0 sc1"
                         : "=v"(f) : "v"(fp + tid));
            asm volatile("s_waitcnt vmcnt(0)" ::: "memory");
            bool ok = (f.x >= target) & (f.y >= target) &
                      (f.z >= target) & (f.w >= target);
            if (__all(ok)) break;
            __builtin_amdgcn_s_sleep(2);
        }
    }
    __syncthreads();                                     // release all waves
}

template <int LAYER>
__device__ void run_layer(int tu, int tid, int wg,
                          const ushort_t* __restrict__ pack,
                          const float* __restrict__ bsum,
                          const ushort_t* __restrict__ xbf,
                          ushort_t* __restrict__ hbuf0,
                          ushort_t* __restrict__ hbuf1,
                          unsigned int* __restrict__ flags)
{
    constexpr int NK = LAYER ? 32 : 18;
    int l = tid & 63, v = tid >> 6;
    int u_loc = l >> 4;
    int bb = v * 16 + (l & 15);
    int u = tu * 4 + u_loc;
    int g8 = u_loc * 8;

    // A-fragments: resident in VGPRs/AGPRs for the whole sequence.
    bf16x8_t aF[NK];
    {
        const ushort_t* src = pack + (size_t)tu * (NK * 512) + l * 8;
#pragma unroll
        for (int kk = 0; kk < NK; ++kk)
            aF[kk] = *(const bf16x8_t*)(src + kk * 512);
    }
    const float* bp = bsum + LAYER * 2048 + u * 4;
    float bi0 = bp[0], bi1 = bp[1], bi2 = bp[2], bi3 = bp[3];
    float creg = 0.0f;                              // cell state, lane-local

    const int HS = 64 * 512;
    for (int k = 0; k <= T_; ++k) {
        bool active = LAYER ? (k >= 1) : (k < T_);
        if (active) {
            // both layers read h0[k-1] from slot (k+1)&1
            const ushort_t* h0r = hbuf0 + ((k + 1) & 1) * HS + bb * 512;
            // layer0 K-tail: x_t (read-only, plain cached);
            // layer1 K-tail: h1[k-2] slot k&1 (sc1)
            const ushort_t* srcHi = LAYER ? (hbuf1 + (k & 1) * HS + bb * 512)
                                          : (xbf + (size_t)k * 4096 + bb * 64);
            // prefetch ALL B-fragments: pipelined sc1 dwordx4 loads, one latency
            bf16x8_t bfr[NK];
#pragma unroll
            for (int kk = 0; kk < NK; ++kk) {
                if (!LAYER && kk >= 16) {
                    bfr[kk] = *(const bf16x8_t*)(srcHi + (kk - 16) * 32 + g8);
                } else {
                    const ushort_t* q = (kk < 16) ? (h0r + kk * 32 + g8)
                                                  : (srcHi + (kk - 16) * 32 + g8);
                    asm volatile("global_load_dwordx4 %0, %1, off sc0 sc1"
                                 : "=v"(bfr[kk]) : "v"(q));
                }
            }
            asm volatile("s_waitcnt vmcnt(0)" ::: "memory");
            __builtin_amdgcn_sched_barrier(0);
            f32x4_t acc  = {bi0, bi1, bi2, bi3};
            f32x4_t acc2 = {0.f, 0.f, 0.f, 0.f};
#pragma unroll
            for (int kk = 0; kk < NK; ++kk) {
                if (kk & 1)
                    acc2 = __builtin_amdgcn_mfma_f32_16x16x32_bf16(aF[kk], bfr[kk], acc2, 0, 0, 0);
                else
                    acc  = __builtin_amdgcn_mfma_f32_16x16x32_bf16(aF[kk], bfr[kk], acc, 0, 0, 0);
            }
            acc = acc + acc2;
            // lane-local LSTM pointwise: regs = i,f,g,o of (u, bb)
            float xi = sigm(acc[0]);
            float xf = sigm(acc[1]);
            float xg = tanhf_(acc[2]);
            float xo = sigm(acc[3]);
            creg = xf * creg + xi * xg;
            float hn = xo * tanhf_(creg);
            // layer0 writes h0[k] slot k&1; layer1 writes h1[k-1] slot (k+1)&1
            ushort_t* hw = LAYER ? (hbuf1 + ((k + 1) & 1) * HS)
                                 : (hbuf0 + (k & 1) * HS);
            // pair lanes (u, u+1) of same bb -> one 4B relaxed sc1 store
            unsigned int mine = (unsigned int)f2bf(hn);
            unsigned int other = (unsigned int)__shfl_xor((int)mine, 16, 64);
            if ((u_loc & 1) == 0) {
                unsigned int valp = mine | (other << 16);
                __hip_atomic_store((unsigned int*)(hw + (size_t)bb * 512 + u), valp,
                                   __ATOMIC_RELAXED, __HIP_MEMORY_SCOPE_AGENT);
            }
        }
        if (k < T_)                                  // last iter: no one reads after
            grid_barrier(flags, k, tid, wg);
    }
}

__global__ __launch_bounds__(256, 1) void lstm_persist(
    const ushort_t* __restrict__ packL0, const ushort_t* __restrict__ packL1,
    const float* __restrict__ bsum, const ushort_t* __restrict__ xbf,
    ushort_t* __restrict__ hbuf0, ushort_t* __restrict__ hbuf1,
    unsigned int* __restrict__ flags)
{
    int w = blockIdx.x, tid = threadIdx.x;
    if (w < 128)
        run_layer<0>(w, tid, w, packL0, bsum, xbf, hbuf0, hbuf1, flags);
    else
        run_layer<1>(w - 128, tid, w, packL1, bsum, xbf, hbuf0, hbuf1, flags);
}

// ---- decoder GEMM: out[64][ncols] = act[64][K] @ W[ncols][K]^T + bias ------
template <int NK, bool RELU, bool OUTBF>
__global__ __launch_bounds__(256) void dec_gemm(
    const float* __restrict__ W, const float* __restrict__ bias,
    const ushort_t* __restrict__ act, void* __restrict__ outp, int ncols)
{
    int tile = blockIdx.x, tid = threadIdx.x;
    int l = tid & 63, v = tid >> 6;
    int bb = v * 16 + (l & 15);
    int jA = tile * 16 + (l & 15);
    int g8 = (l >> 4) * 8;
    const float* wrow = W + (size_t)jA * (NK * 32);
    const ushort_t* arow = act + (size_t)bb * (NK * 32);
    f32x4_t acc = {0.f, 0.f, 0.f, 0.f};
    for (int kk = 0; kk < NK; ++kk) {
        int kg = kk * 32 + g8;
        float4 w0 = *(const float4*)(wrow + kg);
        float4 w1 = *(const float4*)(wrow + kg + 4);
        bf16x8_t af;
        af[0] = (short)f2bf(w0.x); af[1] = (short)f2bf(w0.y);
        af[2] = (short)f2bf(w0.z); af[3] = (short)f2bf(w0.w);
        af[4] = (short)f2bf(w1.x); af[5] = (short)f2bf(w1.y);
        af[6] = (short)f2bf(w1.z); af[7] = (short)f2bf(w1.w);
        bf16x8_t bf = *(const bf16x8_t*)(arow + kg);
        acc = __builtin_amdgcn_mfma_f32_16x16x32_bf16(af, bf, acc, 0, 0, 0);
    }
    int j0 = tile * 16 + (l >> 4) * 4;
    float r[4];
#pragma unroll
    for (int i = 0; i < 4; i++) {
        r[i] = acc[i] + bias[j0 + i];
        if (RELU) r[i] = fmaxf(r[i], 0.f);
    }
    if (OUTBF) {
        ushort_t* o = (ushort_t*)outp + (size_t)bb * ncols + j0;
        unsigned int lo = (unsigned)f2bf(r[0]) | ((unsigned)f2bf(r[1]) << 16);
        unsigned int hi = (unsigned)f2bf(r[2]) | ((unsigned)f2bf(r[3]) << 16);
        uint2 q; q.x = lo; q.y = hi;
        *(uint2*)o = q;
    } else {
        float* o = (float*)outp + (size_t)bb * ncols + j0;
        float4 t4; t4.x = r[0]; t4.y = r[1]; t4.z = r[2]; t4.w = r[3];
        *(float4*)o = t4;
    }
}

// ---- host ------------------------------------------------------------------
extern "C" void kernel_launch(void* const* d_in, const int* in_sizes, int n_in,
                              void* d_out, int out_size, void* d_ws, size_t ws_size,
                              hipStream_t stream)
{
    const float* x    = (const float*)d_in[0];
    const float* Wih0 = (const float*)d_in[1];
    const float* Whh0 = (const float*)d_in[2];
    const float* bih0 = (const float*)d_in[3];
    const float* bhh0 = (const float*)d_in[4];
    const float* Wih1 = (const float*)d_in[5];
    const float* Whh1 = (const float*)d_in[6];
    const float* bih1 = (const float*)d_in[7];
    const float* bhh1 = (const float*)d_in[8];
    const float* W1   = (const float*)d_in[9];
    const float* b1   = (const float*)d_in[10];
    const float* W2   = (const float*)d_in[11];
    const float* b2   = (const float*)d_in[12];
    const float* W3   = (const float*)d_in[13];
    const float* b3   = (const float*)d_in[14];

    char* ws = (char*)d_ws;
    size_t off = 0;
    auto take = [&](size_t bytes) -> char* {
        char* p = ws + off;
        off = (off + bytes + 255) & ~(size_t)255;
        return p;
    };
    ushort_t* packL0 = (ushort_t*)take((size_t)128 * 18 * 64 * 8 * 2);  // 2.25 MiB
    ushort_t* packL1 = (ushort_t*)take((size_t)128 * 32 * 64 * 8 * 2);  // 4 MiB
    float*    bsum   = (float*)take(2 * 2048 * 4);
    ushort_t* xbf    = (ushort_t*)take((size_t)512 * 64 * 64 * 2);      // 4 MiB
    char* zbase = ws + off;
    ushort_t* hbuf0  = (ushort_t*)take(2 * 64 * 512 * 2);
    ushort_t* hbuf1  = (ushort_t*)take(2 * 64 * 512 * 2);
    unsigned int* flags = (unsigned int*)take(256 * 4);
    size_t zbytes = (size_t)((ws + off) - zbase);
    ushort_t* y1 = (ushort_t*)take(64 * 1024 * 2);
    ushort_t* y2 = (ushort_t*)take(64 * 2048 * 2);
    if (off > ws_size) {
        fprintf(stderr, "kernel_launch: ws too small: need %zu have %zu\n", off, ws_size);
        return;
    }

    // prep (every call; deterministic)
    pack_l0<<<(128 * 18 * 64) / 256, 256, 0, stream>>>(Wih0, Whh0, packL0);
    pack_l1<<<(128 * 32 * 64) / 256, 256, 0, stream>>>(Wih1, Whh1, packL1);
    pack_bias<<<16, 256, 0, stream>>>(bih0, bhh0, bih1, bhh1, bsum);
    conv_x<<<(64 * 512 * 64) / 256, 256, 0, stream>>>(x, xbf);
    hipMemsetAsync(zbase, 0, zbytes, stream);   // zero h rings + barrier flags

    // whole recurrence in one persistent kernel (513 internal iterations)
    lstm_persist<<<256, 256, 0, stream>>>(packL0, packL1, bsum, xbf,
                                          hbuf0, hbuf1, flags);

    // final top hidden state h1[511] lives in slot 1
    const ushort_t* h1f = hbuf1 + 1 * (64 * 512);
    dec_gemm<16, true,  true ><<<  64, 256, 0, stream>>>(W1, b1, h1f, y1, D1_);
    dec_gemm<32, true,  true ><<< 128, 256, 0, stream>>>(W2, b2, y1, y2, D2_);
    dec_gemm<64, false, false><<<1024, 256, 0, stream>>>(W3, b3, y2, d_out, O_);
}

// Round 6
// 5351.751 us; speedup vs baseline: 2.2077x; 1.0144x over previous
//
#include <hip/hip_runtime.h>
#include <hip/hip_bf16.h>
#include <cstdio>

// SHRED: 2-layer LSTM (B=64,T=512,I=64,H=512) + MLP decoder 512->1024->2048->16384.
//
// Round 6: weights in LDS, h-fragments in registers -> no scratch spills.
//   R5 post-mortem: VGPR_Count=148 << ~280 needed => aF[] (weights) spilled to
//   scratch; per-step scratch reloads on the MFMA critical path ~= the missing
//   ~5us/step. Fix: stage the WG's weight pack into LDS ONCE (L1: 32KB,
//   L0: 18KB), read A-frags per step via ds_read_b128 (lane-contiguous 16B,
//   conflict-free, ~0.4us/CU/step, overlapped with global B-loads).
//   Register budget ~190 (bfr[32]=128 + rolling A + acc) -> fits, no spill.
// Barrier protocol (fence-free, from R4/R5): h stores sc1 -> vmcnt(0) ->
//   __syncthreads -> tid0 flag store (sc1) -> wave0 polls all 256 flags
//   (dwordx4 sc1) -> __syncthreads.
// WG w<128: layer0 utile w; else layer1 utile w-128. Pipeline-skewed:
//   iteration k computes h0[k] and h1[k-1]; 1 barrier per iteration.
// A-tile row order j_local = u_local*4 + gate => lane's 4 acc regs = i,f,g,o
// of one (unit,batch) pair -> pointwise update lane-local; cell state in reg.

#define B_  64
#define T_  512
#define I_  64
#define H_  512
#define D1_ 1024
#define D2_ 2048
#define O_  16384

typedef __attribute__((ext_vector_type(8))) short bf16x8_t;
typedef __attribute__((ext_vector_type(4))) float f32x4_t;
typedef unsigned short ushort_t;

__device__ inline ushort_t f2bf(float f) {
    return __builtin_bit_cast(ushort_t, __float2bfloat16(f));
}
__device__ inline float sigm(float x) { return 1.0f / (1.0f + __expf(-x)); }
__device__ inline float tanhf_(float x) {
    float cx = fminf(fmaxf(x, -15.f), 15.f);
    float e = __expf(2.f * cx);
    return (e - 1.f) / (e + 1.f);
}

// ---- prep kernels (run once per call, cheap) -------------------------------

// packL0: [128 utiles][18 ksteps][64 lanes][8] bf16.
// A-frag: lane l holds rows j_local=l&15, k = kk*32 + 8*(l>>4) + i.
// j_local = u_local*4 + gate; weight row = gate*H + u.
// K-concat for layer0: [h0_prev (512) ; x_t (64)] -> Whh0 then Wih0.
__global__ void pack_l0(const float* __restrict__ Wih0, const float* __restrict__ Whh0,
                        ushort_t* __restrict__ pack) {
    int idx = blockIdx.x * 256 + threadIdx.x;       // < 128*18*64
    int l  = idx & 63;
    int kk = (idx >> 6) % 18;
    int tu = idx / (18 * 64);
    int jl = l & 15, g8 = (l >> 4) * 8;
    int gate = jl & 3, u = tu * 4 + (jl >> 2);
    int wrow = gate * H_ + u;
    int kg = kk * 32 + g8;                          // chunk of 8 never straddles 512
    const float* s = (kg < H_) ? (Whh0 + (size_t)wrow * H_ + kg)
                               : (Wih0 + (size_t)wrow * I_ + (kg - H_));
    ushort_t* d = pack + (size_t)idx * 8;
#pragma unroll
    for (int i = 0; i < 8; i++) d[i] = f2bf(s[i]);
}

// packL1: [128][32][64][8]. K-concat: [h0_t (512); h1_prev (512)] -> Wih1 then Whh1.
__global__ void pack_l1(const float* __restrict__ Wih1, const float* __restrict__ Whh1,
                        ushort_t* __restrict__ pack) {
    int idx = blockIdx.x * 256 + threadIdx.x;       // < 128*32*64
    int l  = idx & 63;
    int kk = (idx >> 6) & 31;
    int tu = idx >> 11;
    int jl = l & 15, g8 = (l >> 4) * 8;
    int gate = jl & 3, u = tu * 4 + (jl >> 2);
    int wrow = gate * H_ + u;
    int kg = kk * 32 + g8;
    const float* s = (kg < H_) ? (Wih1 + (size_t)wrow * H_ + kg)
                               : (Whh1 + (size_t)wrow * H_ + (kg - H_));
    ushort_t* d = pack + (size_t)idx * 8;
#pragma unroll
    for (int i = 0; i < 8; i++) d[i] = f2bf(s[i]);
}

// bsum[layer][u][gate] = bih[gate*H+u] + bhh[gate*H+u]
__global__ void pack_bias(const float* __restrict__ bih0, const float* __restrict__ bhh0,
                          const float* __restrict__ bih1, const float* __restrict__ bhh1,
                          float* __restrict__ bsum) {
    int idx = blockIdx.x * 256 + threadIdx.x;       // < 4096
    int layer = idx >> 11;
    int rest = idx & 2047;
    int u = rest >> 2, gate = rest & 3;
    const float* a = layer ? bih1 : bih0;
    const float* b = layer ? bhh1 : bhh0;
    bsum[idx] = a[gate * H_ + u] + b[gate * H_ + u];
}

// x[B][T][I] fp32 -> xbf[T][B][I] bf16
__global__ void conv_x(const float* __restrict__ x, ushort_t* __restrict__ xbf) {
    int idx = blockIdx.x * 256 + threadIdx.x;       // < 64*512*64
    int c = idx & 63;
    int t = (idx >> 6) & 511;
    int b = idx >> 15;
    xbf[(size_t)t * 4096 + b * 64 + c] = f2bf(x[idx]);
}

// ---- persistent recurrent kernel -------------------------------------------

// Fence-free barrier. flags[w] = completed iters of WG w (monotone, sc1).
__device__ inline void grid_barrier(unsigned int* flags, int iter, int tid, int wg) {
    asm volatile("s_waitcnt vmcnt(0)" ::: "memory");    // own stores at MALL
    __syncthreads();                                     // whole WG done
    unsigned int target = (unsigned int)(iter + 1);
    if (tid == 0)
        __hip_atomic_store(&flags[wg], target, __ATOMIC_RELAXED,
                           __HIP_MEMORY_SCOPE_AGENT);
    if (tid < 64) {
        const uint4* fp = (const uint4*)flags;
        for (;;) {
            uint4 f;
            asm volatile("global_load_dwordx4 %0, %1, off sc0 sc1"
                         : "=v"(f) : "v"(fp + tid));
            asm volatile("s_waitcnt vmcnt(0)" ::: "memory");
            bool ok = (f.x >= target) & (f.y >= target) &
                      (f.z >= target) & (f.w >= target);
            if (__all(ok)) break;
            __builtin_amdgcn_s_sleep(2);
        }
    }
    __syncthreads();                                     // release all waves
}

template <int LAYER>
__device__ void run_layer(int tu, int tid, int wg,
                          const ushort_t* __restrict__ pack,
                          const float* __restrict__ bsum,
                          const ushort_t* __restrict__ xbf,
                          ushort_t* __restrict__ hbuf0,
                          ushort_t* __restrict__ hbuf1,
                          unsigned int* __restrict__ flags,
                          uint4* aLDS)
{
    constexpr int NK = LAYER ? 32 : 18;
    int l = tid & 63, v = tid >> 6;
    int u_loc = l >> 4;
    int bb = v * 16 + (l & 15);
    int u = tu * 4 + u_loc;
    int g8 = u_loc * 8;

    // Stage this WG's weight pack into LDS ONCE (kk-slab = 64 lanes x 16B = 1KB).
    {
        const uint4* s4 = (const uint4*)(pack + (size_t)tu * (NK * 512));
        for (int i = tid; i < NK * 64; i += 256) aLDS[i] = s4[i];
    }
    __syncthreads();
    const bf16x8_t* aFr = (const bf16x8_t*)aLDS;

    const float* bp = bsum + LAYER * 2048 + u * 4;
    float bi0 = bp[0], bi1 = bp[1], bi2 = bp[2], bi3 = bp[3];
    float creg = 0.0f;                              // cell state, lane-local

    const int HS = 64 * 512;
    for (int k = 0; k <= T_; ++k) {
        bool active = LAYER ? (k >= 1) : (k < T_);
        if (active) {
            // both layers read h0[k-1] from slot (k+1)&1
            const ushort_t* h0r = hbuf0 + ((k + 1) & 1) * HS + bb * 512;
            // layer0 K-tail: x_t (read-only, plain cached);
            // layer1 K-tail: h1[k-2] slot k&1 (sc1)
            const ushort_t* srcHi = LAYER ? (hbuf1 + (k & 1) * HS + bb * 512)
                                          : (xbf + (size_t)k * 4096 + bb * 64);
            // prefetch ALL B-fragments: pipelined sc1 dwordx4 loads, one latency
            bf16x8_t bfr[NK];
#pragma unroll
            for (int kk = 0; kk < NK; ++kk) {
                if (!LAYER && kk >= 16) {
                    bfr[kk] = *(const bf16x8_t*)(srcHi + (kk - 16) * 32 + g8);
                } else {
                    const ushort_t* q = (kk < 16) ? (h0r + kk * 32 + g8)
                                                  : (srcHi + (kk - 16) * 32 + g8);
                    asm volatile("global_load_dwordx4 %0, %1, off sc0 sc1"
                                 : "=v"(bfr[kk]) : "v"(q));
                }
            }
            asm volatile("s_waitcnt vmcnt(0)" ::: "memory");
            __builtin_amdgcn_sched_barrier(0);
            f32x4_t acc  = {bi0, bi1, bi2, bi3};
            f32x4_t acc2 = {0.f, 0.f, 0.f, 0.f};
#pragma unroll
            for (int kk = 0; kk < NK; ++kk) {
                bf16x8_t a = aFr[kk * 64 + l];      // ds_read_b128, compiler-sched
                if (kk & 1)
                    acc2 = __builtin_amdgcn_mfma_f32_16x16x32_bf16(a, bfr[kk], acc2, 0, 0, 0);
                else
                    acc  = __builtin_amdgcn_mfma_f32_16x16x32_bf16(a, bfr[kk], acc, 0, 0, 0);
            }
            acc = acc + acc2;
            // lane-local LSTM pointwise: regs = i,f,g,o of (u, bb)
            float xi = sigm(acc[0]);
            float xf = sigm(acc[1]);
            float xg = tanhf_(acc[2]);
            float xo = sigm(acc[3]);
            creg = xf * creg + xi * xg;
            float hn = xo * tanhf_(creg);
            // layer0 writes h0[k] slot k&1; layer1 writes h1[k-1] slot (k+1)&1
            ushort_t* hw = LAYER ? (hbuf1 + ((k + 1) & 1) * HS)
                                 : (hbuf0 + (k & 1) * HS);
            // pair lanes (u, u+1) of same bb -> one 4B relaxed sc1 store
            unsigned int mine = (unsigned int)f2bf(hn);
            unsigned int other = (unsigned int)__shfl_xor((int)mine, 16, 64);
            if ((u_loc & 1) == 0) {
                unsigned int valp = mine | (other << 16);
                __hip_atomic_store((unsigned int*)(hw + (size_t)bb * 512 + u), valp,
                                   __ATOMIC_RELAXED, __HIP_MEMORY_SCOPE_AGENT);
            }
        }
        if (k < T_)                                  // last iter: no one reads after
            grid_barrier(flags, k, tid, wg);
    }
}

__global__ __launch_bounds__(256, 1) void lstm_persist(
    const ushort_t* __restrict__ packL0, const ushort_t* __restrict__ packL1,
    const float* __restrict__ bsum, const ushort_t* __restrict__ xbf,
    ushort_t* __restrict__ hbuf0, ushort_t* __restrict__ hbuf1,
    unsigned int* __restrict__ flags)
{
    __shared__ uint4 aLDS[2048];                    // 32 KiB weight pack
    int w = blockIdx.x, tid = threadIdx.x;
    if (w < 128)
        run_layer<0>(w, tid, w, packL0, bsum, xbf, hbuf0, hbuf1, flags, aLDS);
    else
        run_layer<1>(w - 128, tid, w, packL1, bsum, xbf, hbuf0, hbuf1, flags, aLDS);
}

// ---- decoder GEMM: out[64][ncols] = act[64][K] @ W[ncols][K]^T + bias ------
template <int NK, bool RELU, bool OUTBF>
__global__ __launch_bounds__(256) void dec_gemm(
    const float* __restrict__ W, const float* __restrict__ bias,
    const ushort_t* __restrict__ act, void* __restrict__ outp, int ncols)
{
    int tile = blockIdx.x, tid = threadIdx.x;
    int l = tid & 63, v = tid >> 6;
    int bb = v * 16 + (l & 15);
    int jA = tile * 16 + (l & 15);
    int g8 = (l >> 4) * 8;
    const float* wrow = W + (size_t)jA * (NK * 32);
    const ushort_t* arow = act + (size_t)bb * (NK * 32);
    f32x4_t acc = {0.f, 0.f, 0.f, 0.f};
    for (int kk = 0; kk < NK; ++kk) {
        int kg = kk * 32 + g8;
        float4 w0 = *(const float4*)(wrow + kg);
        float4 w1 = *(const float4*)(wrow + kg + 4);
        bf16x8_t af;
        af[0] = (short)f2bf(w0.x); af[1] = (short)f2bf(w0.y);
        af[2] = (short)f2bf(w0.z); af[3] = (short)f2bf(w0.w);
        af[4] = (short)f2bf(w1.x); af[5] = (short)f2bf(w1.y);
        af[6] = (short)f2bf(w1.z); af[7] = (short)f2bf(w1.w);
        bf16x8_t bf = *(const bf16x8_t*)(arow + kg);
        acc = __builtin_amdgcn_mfma_f32_16x16x32_bf16(af, bf, acc, 0, 0, 0);
    }
    int j0 = tile * 16 + (l >> 4) * 4;
    float r[4];
#pragma unroll
    for (int i = 0; i < 4; i++) {
        r[i] = acc[i] + bias[j0 + i];
        if (RELU) r[i] = fmaxf(r[i], 0.f);
    }
    if (OUTBF) {
        ushort_t* o = (ushort_t*)outp + (size_t)bb * ncols + j0;
        unsigned int lo = (unsigned)f2bf(r[0]) | ((unsigned)f2bf(r[1]) << 16);
        unsigned int hi = (unsigned)f2bf(r[2]) | ((unsigned)f2bf(r[3]) << 16);
        uint2 q; q.x = lo; q.y = hi;
        *(uint2*)o = q;
    } else {
        float* o = (float*)outp + (size_t)bb * ncols + j0;
        float4 t4; t4.x = r[0]; t4.y = r[1]; t4.z = r[2]; t4.w = r[3];
        *(float4*)o = t4;
    }
}

// ---- host ------------------------------------------------------------------
extern "C" void kernel_launch(void* const* d_in, const int* in_sizes, int n_in,
                              void* d_out, int out_size, void* d_ws, size_t ws_size,
                              hipStream_t stream)
{
    const float* x    = (const float*)d_in[0];
    const float* Wih0 = (const float*)d_in[1];
    const float* Whh0 = (const float*)d_in[2];
    const float* bih0 = (const float*)d_in[3];
    const float* bhh0 = (const float*)d_in[4];
    const float* Wih1 = (const float*)d_in[5];
    const float* Whh1 = (const float*)d_in[6];
    const float* bih1 = (const float*)d_in[7];
    const float* bhh1 = (const float*)d_in[8];
    const float* W1   = (const float*)d_in[9];
    const float* b1   = (const float*)d_in[10];
    const float* W2   = (const float*)d_in[11];
    const float* b2   = (const float*)d_in[12];
    const float* W3   = (const float*)d_in[13];
    const float* b3   = (const float*)d_in[14];

    char* ws = (char*)d_ws;
    size_t off = 0;
    auto take = [&](size_t bytes) -> char* {
        char* p = ws + off;
        off = (off + bytes + 255) & ~(size_t)255;
        return p;
    };
    ushort_t* packL0 = (ushort_t*)take((size_t)128 * 18 * 64 * 8 * 2);  // 2.25 MiB
    ushort_t* packL1 = (ushort_t*)take((size_t)128 * 32 * 64 * 8 * 2);  // 4 MiB
    float*    bsum   = (float*)take(2 * 2048 * 4);
    ushort_t* xbf    = (ushort_t*)take((size_t)512 * 64 * 64 * 2);      // 4 MiB
    char* zbase = ws + off;
    ushort_t* hbuf0  = (ushort_t*)take(2 * 64 * 512 * 2);
    ushort_t* hbuf1  = (ushort_t*)take(2 * 64 * 512 * 2);
    unsigned int* flags = (unsigned int*)take(256 * 4);
    size_t zbytes = (size_t)((ws + off) - zbase);
    ushort_t* y1 = (ushort_t*)take(64 * 1024 * 2);
    ushort_t* y2 = (ushort_t*)take(64 * 2048 * 2);
    if (off > ws_size) {
        fprintf(stderr, "kernel_launch: ws too small: need %zu have %zu\n", off, ws_size);
        return;
    }

    // prep (every call; deterministic)
    pack_l0<<<(128 * 18 * 64) / 256, 256, 0, stream>>>(Wih0, Whh0, packL0);
    pack_l1<<<(128 * 32 * 64) / 256, 256, 0, stream>>>(Wih1, Whh1, packL1);
    pack_bias<<<16, 256, 0, stream>>>(bih0, bhh0, bih1, bhh1, bsum);
    conv_x<<<(64 * 512 * 64) / 256, 256, 0, stream>>>(x, xbf);
    hipMemsetAsync(zbase, 0, zbytes, stream);   // zero h rings + barrier flags

    // whole recurrence in one persistent kernel (513 internal iterations)
    lstm_persist<<<256, 256, 0, stream>>>(packL0, packL1, bsum, xbf,
                                          hbuf0, hbuf1, flags);

    // final top hidden state h1[511] lives in slot 1
    const ushort_t* h1f = hbuf1 + 1 * (64 * 512);
    dec_gemm<16, true,  true ><<<  64, 256, 0, stream>>>(W1, b1, h1f, y1, D1_);
    dec_gemm<32, true,  true ><<< 128, 256, 0, stream>>>(W2, b2, y1, y2, D2_);
    dec_gemm<64, false, false><<<1024, 256, 0, stream>>>(W3, b3, y2, d_out, O_);
}